// Round 5
// baseline (785.244 us; speedup 1.0000x reference)
//
#include <hip/hip_runtime.h>

#define EMBED 128
#define NRBF 6
#define VOCAB 100
#define EBLOCK 1024
#define EGRID 512
// floats in the staged table region: T1 (100*128) + T2 (100*128) + Wc (6*128)
#define TABLE_F (VOCAB * EMBED * 2 + NRBF * EMBED)   // 26368 floats = 105472 B

// ---------------------------------------------------------------------------
// Precompute (unchanged):
//   T1[v][d] = sum_j emb[v][j] * Wd[j][d]        + b[d]   (bias folded)
//   T2[v][d] = sum_j emb[v][j] * Wd[128+j][d]
//   Wc[k][d] = sum_j W_edge[k][j] * Wd[256+j][d]
// ---------------------------------------------------------------------------
__global__ __launch_bounds__(EMBED) void precompute_kernel(
    const float* __restrict__ W_edge,
    const float* __restrict__ emb,
    const float* __restrict__ Wd,
    const float* __restrict__ b,
    float* __restrict__ T1,
    float* __restrict__ T2,
    float* __restrict__ Wc)
{
    const int d = threadIdx.x;
    const int v = blockIdx.x;
    if (v < VOCAB) {
        __shared__ float hrow[EMBED];
        hrow[d] = emb[v * EMBED + d];
        __syncthreads();
        float acc1 = b[d];
        float acc2 = 0.0f;
        #pragma unroll 8
        for (int j = 0; j < EMBED; ++j) {
            const float hv = hrow[j];
            acc1 += hv * Wd[j * EMBED + d];
            acc2 += hv * Wd[(EMBED + j) * EMBED + d];
        }
        T1[v * EMBED + d] = acc1;
        T2[v * EMBED + d] = acc2;
    } else {
        const int k = v - VOCAB;
        float acc = 0.0f;
        #pragma unroll 8
        for (int j = 0; j < EMBED; ++j)
            acc += W_edge[k * EMBED + j] * Wd[(2 * EMBED + j) * EMBED + d];
        Wc[k * EMBED + d] = acc;
    }
}

// ---------------------------------------------------------------------------
// V1: store-only probe. Same geometry/addresses as the full kernel, no loads.
// Isolates the write path. R passes, memory-clobber between passes (no DSE).
// ---------------------------------------------------------------------------
__global__ __launch_bounds__(EBLOCK) void v1_store_probe(
    float* __restrict__ out, int E, int CH, int R)
{
    const int lane = threadIdx.x & 31;
    const int d    = lane * 4;
    const int gid  = (blockIdx.x * EBLOCK + threadIdx.x) >> 5;
    const int e0 = gid * CH;
    const int e1 = min(e0 + CH, E);

    for (int r = 0; r < R; ++r) {
        const float4 v = make_float4((float)(d + r), (float)d, (float)d, (float)d);
        #pragma unroll 4
        for (int e = e0; e < e1; ++e)
            *reinterpret_cast<float4*>(out + (long)e * EMBED + d) = v;
        asm volatile("" ::: "memory");
    }
}

// ---------------------------------------------------------------------------
// V2: + the dependent load chain (nbr -> z gathers) and e_rbf streams.
// No table reads, no FMA block, no silu. V2 - V1 = load-chain cost.
// ---------------------------------------------------------------------------
__global__ __launch_bounds__(EBLOCK) void v2_chain_probe(
    const float* __restrict__ e_rbf,
    const int*   __restrict__ z,
    const int*   __restrict__ nbr,
    float* __restrict__ out, int E, int CH, int R)
{
    const int lane = threadIdx.x & 31;
    const int d    = lane * 4;
    const int gid  = (blockIdx.x * EBLOCK + threadIdx.x) >> 5;
    const int e0 = gid * CH;
    const int e1 = min(e0 + CH, E);

    for (int r = 0; r < R; ++r) {
        #pragma unroll 4
        for (int e = e0; e < e1; ++e) {
            const int2 nn = *reinterpret_cast<const int2*>(nbr + 2 * e);
            const int za = z[nn.x];
            const int zb = z[nn.y];
            const float* er = e_rbf + (long)e * NRBF;
            const float2 f01 = *reinterpret_cast<const float2*>(er + 0);
            const float2 f23 = *reinterpret_cast<const float2*>(er + 2);
            const float2 f45 = *reinterpret_cast<const float2*>(er + 4);
            const float v = (float)(za + zb + r)
                          + f01.x + f01.y + f23.x + f23.y + f45.x + f45.y;
            *reinterpret_cast<float4*>(out + (long)e * EMBED + d) =
                make_float4(v, v, v, v);
        }
        asm volatile("" ::: "memory");
    }
}

// ---------------------------------------------------------------------------
// V3: the FULL kernel (correct output) with guaranteed-native silu:
// __expf -> v_exp_f32, __builtin_amdgcn_rcpf -> v_rcp_f32 (no IEEE div chain).
// Runs R passes; every pass writes the correct result, so the last pass
// leaves d_out valid.
// ---------------------------------------------------------------------------
__global__ __launch_bounds__(EBLOCK) void v3_full(
    const float* __restrict__ e_rbf,
    const int*   __restrict__ z,
    const int*   __restrict__ nbr,
    const float* __restrict__ tables,
    float* __restrict__ out, int E, int CH, int R)
{
    extern __shared__ float smem[];
    float* T1s = smem;
    float* T2s = smem + VOCAB * EMBED;
    float* Wcs = smem + 2 * VOCAB * EMBED;

    {
        const float4* src = reinterpret_cast<const float4*>(tables);
        float4* dst = reinterpret_cast<float4*>(smem);
        for (int i = threadIdx.x; i < TABLE_F / 4; i += EBLOCK)
            dst[i] = src[i];
    }
    __syncthreads();

    const int lane = threadIdx.x & 31;
    const int d    = lane * 4;
    const int gid  = (blockIdx.x * EBLOCK + threadIdx.x) >> 5;
    const int e0 = gid * CH;
    const int e1 = min(e0 + CH, E);

    const float4 wc0 = *reinterpret_cast<const float4*>(Wcs + 0 * EMBED + d);
    const float4 wc1 = *reinterpret_cast<const float4*>(Wcs + 1 * EMBED + d);
    const float4 wc2 = *reinterpret_cast<const float4*>(Wcs + 2 * EMBED + d);
    const float4 wc3 = *reinterpret_cast<const float4*>(Wcs + 3 * EMBED + d);
    const float4 wc4 = *reinterpret_cast<const float4*>(Wcs + 4 * EMBED + d);
    const float4 wc5 = *reinterpret_cast<const float4*>(Wcs + 5 * EMBED + d);

    for (int r = 0; r < R; ++r) {
        #pragma unroll 4
        for (int e = e0; e < e1; ++e) {
            const int2 nn = *reinterpret_cast<const int2*>(nbr + 2 * e);
            const int za = z[nn.x];
            const int zb = z[nn.y];

            const float* er = e_rbf + (long)e * NRBF;
            const float2 f01 = *reinterpret_cast<const float2*>(er + 0);
            const float2 f23 = *reinterpret_cast<const float2*>(er + 2);
            const float2 f45 = *reinterpret_cast<const float2*>(er + 4);

            float4 acc = *reinterpret_cast<const float4*>(T1s + za * EMBED + d);
            const float4 t2 = *reinterpret_cast<const float4*>(T2s + zb * EMBED + d);
            acc.x += t2.x; acc.y += t2.y; acc.z += t2.z; acc.w += t2.w;

            acc.x += f01.x * wc0.x; acc.y += f01.x * wc0.y; acc.z += f01.x * wc0.z; acc.w += f01.x * wc0.w;
            acc.x += f01.y * wc1.x; acc.y += f01.y * wc1.y; acc.z += f01.y * wc1.z; acc.w += f01.y * wc1.w;
            acc.x += f23.x * wc2.x; acc.y += f23.x * wc2.y; acc.z += f23.x * wc2.z; acc.w += f23.x * wc2.w;
            acc.x += f23.y * wc3.x; acc.y += f23.y * wc3.y; acc.z += f23.y * wc3.z; acc.w += f23.y * wc3.w;
            acc.x += f45.x * wc4.x; acc.y += f45.x * wc4.y; acc.z += f45.x * wc4.z; acc.w += f45.x * wc4.w;
            acc.x += f45.y * wc5.x; acc.y += f45.y * wc5.y; acc.z += f45.y * wc5.z; acc.w += f45.y * wc5.w;

            // silu: x * rcp(1 + exp(-x)) — native v_exp_f32 / v_rcp_f32 only
            float4 rr;
            rr.x = acc.x * __builtin_amdgcn_rcpf(1.0f + __expf(-acc.x));
            rr.y = acc.y * __builtin_amdgcn_rcpf(1.0f + __expf(-acc.y));
            rr.z = acc.z * __builtin_amdgcn_rcpf(1.0f + __expf(-acc.z));
            rr.w = acc.w * __builtin_amdgcn_rcpf(1.0f + __expf(-acc.w));

            *reinterpret_cast<float4*>(out + (long)e * EMBED + d) = rr;
        }
        asm volatile("" ::: "memory");
    }
}

extern "C" void kernel_launch(void* const* d_in, const int* in_sizes, int n_in,
                              void* d_out, int out_size, void* d_ws, size_t ws_size,
                              hipStream_t stream)
{
    // Input order: e_rbf, z, nbr_list, W_edge, emb_table, W_dense, b_dense
    const float* e_rbf  = (const float*)d_in[0];
    const int*   z      = (const int*)  d_in[1];
    const int*   nbr    = (const int*)  d_in[2];
    const float* W_edge = (const float*)d_in[3];
    const float* emb    = (const float*)d_in[4];
    const float* Wd     = (const float*)d_in[5];
    const float* b      = (const float*)d_in[6];
    float* out = (float*)d_out;

    const int E = in_sizes[2] / 2;

    float* T1 = (float*)d_ws;
    float* T2 = T1 + VOCAB * EMBED;
    float* Wc = T2 + VOCAB * EMBED;

    precompute_kernel<<<VOCAB + NRBF, EMBED, 0, stream>>>(W_edge, emb, Wd, b, T1, T2, Wc);

    const int ngroups = EGRID * EBLOCK / 32;          // 16384
    const int CH = (E + ngroups - 1) / ngroups;       // 37

    // Ablation probes (diagnostic round). Internal repeats push each dispatch
    // above the ~176 us harness fills so all three appear in top-5 rocprof.
    v1_store_probe<<<EGRID, EBLOCK, TABLE_F * 4, stream>>>(out, E, CH, 5);
    v2_chain_probe<<<EGRID, EBLOCK, TABLE_F * 4, stream>>>(e_rbf, z, nbr, out, E, CH, 4);
    // Full (correct) kernel LAST — leaves d_out valid.
    v3_full<<<EGRID, EBLOCK, TABLE_F * 4, stream>>>(e_rbf, z, nbr, T1, out, E, CH, 3);
}

// Round 6
// 119.573 us; speedup vs baseline: 6.5671x; 6.5671x over previous
//
#include <hip/hip_runtime.h>

#define EMBED 128
#define NRBF 6
#define VOCAB 100
#define EBLOCK 1024
#define EGRID 256
// floats in the staged table region: T1 (100*128) + T2 (100*128) + Wc (6*128)
#define TABLE_F (VOCAB * EMBED * 2 + NRBF * EMBED)   // 26368 floats = 105472 B

// ---------------------------------------------------------------------------
// Precompute:
//   T1[v][d] = sum_j emb[v][j] * Wd[j][d]        + b[d]   (bias folded)
//   T2[v][d] = sum_j emb[v][j] * Wd[128+j][d]
//   Wc[k][d] = sum_j W_edge[k][j] * Wd[256+j][d]
// ---------------------------------------------------------------------------
__global__ __launch_bounds__(EMBED) void precompute_kernel(
    const float* __restrict__ W_edge,
    const float* __restrict__ emb,
    const float* __restrict__ Wd,
    const float* __restrict__ b,
    float* __restrict__ T1,
    float* __restrict__ T2,
    float* __restrict__ Wc)
{
    const int d = threadIdx.x;
    const int v = blockIdx.x;
    if (v < VOCAB) {
        __shared__ float hrow[EMBED];
        hrow[d] = emb[v * EMBED + d];
        __syncthreads();
        float acc1 = b[d];
        float acc2 = 0.0f;
        #pragma unroll 8
        for (int j = 0; j < EMBED; ++j) {
            const float hv = hrow[j];
            acc1 += hv * Wd[j * EMBED + d];
            acc2 += hv * Wd[(EMBED + j) * EMBED + d];
        }
        T1[v * EMBED + d] = acc1;
        T2[v * EMBED + d] = acc2;
    } else {
        const int k = v - VOCAB;
        float acc = 0.0f;
        #pragma unroll 8
        for (int j = 0; j < EMBED; ++j)
            acc += W_edge[k * EMBED + j] * Wd[(2 * EMBED + j) * EMBED + d];
        Wc[k * EMBED + d] = acc;
    }
}

// ---------------------------------------------------------------------------
// Gather pass: collapse the 2-hop nbr->z chain into a per-edge descriptor.
//   desc[e] = z[nbr[e,0]] | z[nbr[e,1]] << 16
// One thread per edge: 600k independent chains -> latency fully hidden.
// ---------------------------------------------------------------------------
__global__ __launch_bounds__(256) void gather_kernel(
    const int* __restrict__ z,
    const int* __restrict__ nbr,
    unsigned int* __restrict__ desc, int E)
{
    const int e = blockIdx.x * 256 + threadIdx.x;
    if (e < E) {
        const int2 nn = *reinterpret_cast<const int2*>(nbr + 2 * e);
        desc[e] = (unsigned)z[nn.x] | ((unsigned)z[nn.y] << 16);
    }
}

// ---------------------------------------------------------------------------
// Edge kernel (desc path): chain depth 1. Per 32-lane group a contiguous
// chunk of edges; tables in LDS; silu with native v_exp_f32/v_rcp_f32.
//   out[e] = silu(T1[desc.lo] + T2[desc.hi] + e_rbf[e] @ Wc)
// ---------------------------------------------------------------------------
__global__ __launch_bounds__(EBLOCK) void edge_kernel(
    const float* __restrict__ e_rbf,          // [E,6]
    const unsigned int* __restrict__ desc,    // [E]
    const float* __restrict__ tables,         // T1|T2|Wc in ws
    float* __restrict__ out,                  // [E,128]
    int E, int CH)
{
    extern __shared__ float smem[];
    float* T1s = smem;
    float* T2s = smem + VOCAB * EMBED;
    float* Wcs = smem + 2 * VOCAB * EMBED;

    {
        const float4* src = reinterpret_cast<const float4*>(tables);
        float4* dst = reinterpret_cast<float4*>(smem);
        for (int i = threadIdx.x; i < TABLE_F / 4; i += EBLOCK)
            dst[i] = src[i];
    }
    __syncthreads();

    const int lane = threadIdx.x & 31;
    const int d    = lane * 4;
    const int gid  = (blockIdx.x * EBLOCK + threadIdx.x) >> 5;
    const int e0 = gid * CH;
    const int e1 = min(e0 + CH, E);

    const float4 wc0 = *reinterpret_cast<const float4*>(Wcs + 0 * EMBED + d);
    const float4 wc1 = *reinterpret_cast<const float4*>(Wcs + 1 * EMBED + d);
    const float4 wc2 = *reinterpret_cast<const float4*>(Wcs + 2 * EMBED + d);
    const float4 wc3 = *reinterpret_cast<const float4*>(Wcs + 3 * EMBED + d);
    const float4 wc4 = *reinterpret_cast<const float4*>(Wcs + 4 * EMBED + d);
    const float4 wc5 = *reinterpret_cast<const float4*>(Wcs + 5 * EMBED + d);

    #pragma unroll 4
    for (int e = e0; e < e1; ++e) {
        const unsigned dsc = desc[e];                 // group-uniform stream
        const int za = (int)(dsc & 0xffffu) << 7;     // *EMBED
        const int zb = (int)(dsc >> 16) << 7;

        const float* er = e_rbf + (long)e * NRBF;
        const float2 f01 = *reinterpret_cast<const float2*>(er + 0);
        const float2 f23 = *reinterpret_cast<const float2*>(er + 2);
        const float2 f45 = *reinterpret_cast<const float2*>(er + 4);

        float4 acc = *reinterpret_cast<const float4*>(T1s + za + d);
        const float4 t2 = *reinterpret_cast<const float4*>(T2s + zb + d);
        acc.x += t2.x; acc.y += t2.y; acc.z += t2.z; acc.w += t2.w;

        acc.x += f01.x * wc0.x; acc.y += f01.x * wc0.y; acc.z += f01.x * wc0.z; acc.w += f01.x * wc0.w;
        acc.x += f01.y * wc1.x; acc.y += f01.y * wc1.y; acc.z += f01.y * wc1.z; acc.w += f01.y * wc1.w;
        acc.x += f23.x * wc2.x; acc.y += f23.x * wc2.y; acc.z += f23.x * wc2.z; acc.w += f23.x * wc2.w;
        acc.x += f23.y * wc3.x; acc.y += f23.y * wc3.y; acc.z += f23.y * wc3.z; acc.w += f23.y * wc3.w;
        acc.x += f45.x * wc4.x; acc.y += f45.x * wc4.y; acc.z += f45.x * wc4.z; acc.w += f45.x * wc4.w;
        acc.x += f45.y * wc5.x; acc.y += f45.y * wc5.y; acc.z += f45.y * wc5.z; acc.w += f45.y * wc5.w;

        float4 rr;
        rr.x = acc.x * __builtin_amdgcn_rcpf(1.0f + __expf(-acc.x));
        rr.y = acc.y * __builtin_amdgcn_rcpf(1.0f + __expf(-acc.y));
        rr.z = acc.z * __builtin_amdgcn_rcpf(1.0f + __expf(-acc.z));
        rr.w = acc.w * __builtin_amdgcn_rcpf(1.0f + __expf(-acc.w));

        *reinterpret_cast<float4*>(out + (long)e * EMBED + d) = rr;
    }
}

// ---------------------------------------------------------------------------
// Fallback (inline chain) in case ws_size can't hold desc — R4-equivalent.
// ---------------------------------------------------------------------------
__global__ __launch_bounds__(EBLOCK) void edge_kernel_inline(
    const float* __restrict__ e_rbf,
    const int*   __restrict__ z,
    const int*   __restrict__ nbr,
    const float* __restrict__ tables,
    float* __restrict__ out, int E, int CH)
{
    extern __shared__ float smem[];
    float* T1s = smem;
    float* T2s = smem + VOCAB * EMBED;
    float* Wcs = smem + 2 * VOCAB * EMBED;
    {
        const float4* src = reinterpret_cast<const float4*>(tables);
        float4* dst = reinterpret_cast<float4*>(smem);
        for (int i = threadIdx.x; i < TABLE_F / 4; i += EBLOCK)
            dst[i] = src[i];
    }
    __syncthreads();

    const int lane = threadIdx.x & 31;
    const int d    = lane * 4;
    const int gid  = (blockIdx.x * EBLOCK + threadIdx.x) >> 5;
    const int e0 = gid * CH;
    const int e1 = min(e0 + CH, E);

    const float4 wc0 = *reinterpret_cast<const float4*>(Wcs + 0 * EMBED + d);
    const float4 wc1 = *reinterpret_cast<const float4*>(Wcs + 1 * EMBED + d);
    const float4 wc2 = *reinterpret_cast<const float4*>(Wcs + 2 * EMBED + d);
    const float4 wc3 = *reinterpret_cast<const float4*>(Wcs + 3 * EMBED + d);
    const float4 wc4 = *reinterpret_cast<const float4*>(Wcs + 4 * EMBED + d);
    const float4 wc5 = *reinterpret_cast<const float4*>(Wcs + 5 * EMBED + d);

    #pragma unroll 4
    for (int e = e0; e < e1; ++e) {
        const int2 nn = *reinterpret_cast<const int2*>(nbr + 2 * e);
        const int za = z[nn.x] << 7;
        const int zb = z[nn.y] << 7;
        const float* er = e_rbf + (long)e * NRBF;
        const float2 f01 = *reinterpret_cast<const float2*>(er + 0);
        const float2 f23 = *reinterpret_cast<const float2*>(er + 2);
        const float2 f45 = *reinterpret_cast<const float2*>(er + 4);

        float4 acc = *reinterpret_cast<const float4*>(T1s + za + d);
        const float4 t2 = *reinterpret_cast<const float4*>(T2s + zb + d);
        acc.x += t2.x; acc.y += t2.y; acc.z += t2.z; acc.w += t2.w;

        acc.x += f01.x * wc0.x; acc.y += f01.x * wc0.y; acc.z += f01.x * wc0.z; acc.w += f01.x * wc0.w;
        acc.x += f01.y * wc1.x; acc.y += f01.y * wc1.y; acc.z += f01.y * wc1.z; acc.w += f01.y * wc1.w;
        acc.x += f23.x * wc2.x; acc.y += f23.x * wc2.y; acc.z += f23.x * wc2.z; acc.w += f23.x * wc2.w;
        acc.x += f23.y * wc3.x; acc.y += f23.y * wc3.y; acc.z += f23.y * wc3.z; acc.w += f23.y * wc3.w;
        acc.x += f45.x * wc4.x; acc.y += f45.x * wc4.y; acc.z += f45.x * wc4.z; acc.w += f45.x * wc4.w;
        acc.x += f45.y * wc5.x; acc.y += f45.y * wc5.y; acc.z += f45.y * wc5.z; acc.w += f45.y * wc5.w;

        float4 rr;
        rr.x = acc.x * __builtin_amdgcn_rcpf(1.0f + __expf(-acc.x));
        rr.y = acc.y * __builtin_amdgcn_rcpf(1.0f + __expf(-acc.y));
        rr.z = acc.z * __builtin_amdgcn_rcpf(1.0f + __expf(-acc.z));
        rr.w = acc.w * __builtin_amdgcn_rcpf(1.0f + __expf(-acc.w));

        *reinterpret_cast<float4*>(out + (long)e * EMBED + d) = rr;
    }
}

extern "C" void kernel_launch(void* const* d_in, const int* in_sizes, int n_in,
                              void* d_out, int out_size, void* d_ws, size_t ws_size,
                              hipStream_t stream)
{
    // Input order: e_rbf, z, nbr_list, W_edge, emb_table, W_dense, b_dense
    const float* e_rbf  = (const float*)d_in[0];
    const int*   z      = (const int*)  d_in[1];
    const int*   nbr    = (const int*)  d_in[2];
    const float* W_edge = (const float*)d_in[3];
    const float* emb    = (const float*)d_in[4];
    const float* Wd     = (const float*)d_in[5];
    const float* b      = (const float*)d_in[6];
    float* out = (float*)d_out;

    const int E = in_sizes[2] / 2;

    float* T1 = (float*)d_ws;
    float* T2 = T1 + VOCAB * EMBED;
    float* Wc = T2 + VOCAB * EMBED;
    unsigned int* desc = (unsigned int*)(Wc + NRBF * EMBED);

    precompute_kernel<<<VOCAB + NRBF, EMBED, 0, stream>>>(W_edge, emb, Wd, b, T1, T2, Wc);

    const int ngroups = EGRID * EBLOCK / 32;          // 8192
    const int CH = (E + ngroups - 1) / ngroups;       // 74

    const size_t need = (size_t)TABLE_F * 4 + (size_t)E * 4;
    if (ws_size >= need) {
        gather_kernel<<<(E + 255) / 256, 256, 0, stream>>>(z, nbr, desc, E);
        edge_kernel<<<EGRID, EBLOCK, TABLE_F * 4, stream>>>(e_rbf, desc, T1, out, E, CH);
    } else {
        edge_kernel_inline<<<EGRID, EBLOCK, TABLE_F * 4, stream>>>(e_rbf, z, nbr, T1, out, E, CH);
    }
}

// Round 7
// 83.043 us; speedup vs baseline: 9.4558x; 1.4399x over previous
//
#include <hip/hip_runtime.h>

#define EMBED 128
#define NRBF 6
#define VOCAB 100
#define EBLOCK 1024
#define GROUPS 32                 // 32-lane groups per block
#define CPG 37                    // edges per group per half
#define HALF (GROUPS * CPG)       // 1184 edges per half
#define BCHUNK (2 * HALF)         // 2368 edges per block
#define TABLE_F (VOCAB * EMBED * 2 + NRBF * EMBED)   // 26368 floats (105,472 B)
#define RBF_F (HALF * NRBF)                          // 7104 floats (28,416 B)
#define SMEM_BYTES ((TABLE_F + RBF_F) * 4 + HALF * 4) // 138,624 B <= 160 KB

// ---------------------------------------------------------------------------
// Precompute:
//   T1[v][d] = sum_j emb[v][j] * Wd[j][d]        + b[d]   (bias folded)
//   T2[v][d] = sum_j emb[v][j] * Wd[128+j][d]
//   Wc[k][d] = sum_j W_edge[k][j] * Wd[256+j][d]
// ---------------------------------------------------------------------------
__global__ __launch_bounds__(EMBED) void precompute_kernel(
    const float* __restrict__ W_edge,
    const float* __restrict__ emb,
    const float* __restrict__ Wd,
    const float* __restrict__ b,
    float* __restrict__ T1,
    float* __restrict__ T2,
    float* __restrict__ Wc)
{
    const int d = threadIdx.x;
    const int v = blockIdx.x;
    if (v < VOCAB) {
        __shared__ float hrow[EMBED];
        hrow[d] = emb[v * EMBED + d];
        __syncthreads();
        float acc1 = b[d];
        float acc2 = 0.0f;
        #pragma unroll 8
        for (int j = 0; j < EMBED; ++j) {
            const float hv = hrow[j];
            acc1 += hv * Wd[j * EMBED + d];
            acc2 += hv * Wd[(EMBED + j) * EMBED + d];
        }
        T1[v * EMBED + d] = acc1;
        T2[v * EMBED + d] = acc2;
    } else {
        const int k = v - VOCAB;
        float acc = 0.0f;
        #pragma unroll 8
        for (int j = 0; j < EMBED; ++j)
            acc += W_edge[k * EMBED + j] * Wd[(2 * EMBED + j) * EMBED + d];
        Wc[k * EMBED + d] = acc;
    }
}

// ---------------------------------------------------------------------------
// Edge kernel, staged version. Per block: 2368 contiguous edges, two halves.
// Each half: cooperative stage of e_rbf + fused nbr->z descriptors into LDS
// (coalesced / massively parallel -> latency hidden), then a consume loop
// whose ONLY global-memory op is the coalesced output store.
//   out[e] = silu(T1[z[a]] + T2[z[b]] + e_rbf[e] @ Wc)
// ---------------------------------------------------------------------------
__global__ __launch_bounds__(EBLOCK) void edge_kernel(
    const float* __restrict__ e_rbf,   // [E,6]
    const int*   __restrict__ z,       // [N]
    const int*   __restrict__ nbr,     // [E,2]
    const float* __restrict__ tables,  // T1|T2|Wc in ws
    float* __restrict__ out,           // [E,128]
    int E)
{
    extern __shared__ float smem[];
    float* T1s    = smem;                           // [100*128]
    float* T2s    = smem + VOCAB * EMBED;           // [100*128]
    float* Wcs    = smem + 2 * VOCAB * EMBED;       // [6*128]
    float* rbf_s  = smem + TABLE_F;                 // [1184*6]
    int*   desc_s = (int*)(smem + TABLE_F + RBF_F); // [1184]

    const int tid  = threadIdx.x;
    const int base = blockIdx.x * BCHUNK;
    const int lane = tid & 31;
    const int d    = lane * 4;
    const int g    = tid >> 5;

    const float4* erbf4 = reinterpret_cast<const float4*>(e_rbf);
    const int nf4 = (int)(((long)E * NRBF) >> 2);   // total float4s in e_rbf

    // ---- stage tables (once) + half 0 inputs ----
    {
        const float4* src = reinterpret_cast<const float4*>(tables);
        float4* dst = reinterpret_cast<float4*>(smem);
        #pragma unroll 2
        for (int i = tid; i < TABLE_F / 4; i += EBLOCK)
            dst[i] = src[i];
    }
    {
        const int src0 = (base * NRBF) >> 2;        // base*6 % 4 == 0 (base mult of 2368)
        float4* dst = reinterpret_cast<float4*>(rbf_s);
        #pragma unroll 2
        for (int i = tid; i < RBF_F / 4; i += EBLOCK) {
            const int s = src0 + i;
            dst[i] = (s < nf4) ? erbf4[s] : make_float4(0.f, 0.f, 0.f, 0.f);
        }
        #pragma unroll 2
        for (int i = tid; i < HALF; i += EBLOCK) {
            const int e = base + i;
            if (e < E) {
                const int2 nn = *reinterpret_cast<const int2*>(nbr + 2 * e);
                desc_s[i] = z[nn.x] | (z[nn.y] << 16);
            }
        }
    }
    __syncthreads();

    // Wc into registers (stable for whole kernel)
    const float4 wc0 = *reinterpret_cast<const float4*>(Wcs + 0 * EMBED + d);
    const float4 wc1 = *reinterpret_cast<const float4*>(Wcs + 1 * EMBED + d);
    const float4 wc2 = *reinterpret_cast<const float4*>(Wcs + 2 * EMBED + d);
    const float4 wc3 = *reinterpret_cast<const float4*>(Wcs + 3 * EMBED + d);
    const float4 wc4 = *reinterpret_cast<const float4*>(Wcs + 4 * EMBED + d);
    const float4 wc5 = *reinterpret_cast<const float4*>(Wcs + 5 * EMBED + d);

    auto compute_half = [&](int ebase) {
        const int lbase = g * CPG;
        #pragma unroll 4
        for (int i = 0; i < CPG; ++i) {
            const int e = ebase + lbase + i;
            if (e >= E) break;
            const unsigned dsc = (unsigned)desc_s[lbase + i];
            const int za = (int)(dsc & 0xffffu) << 7;
            const int zb = (int)(dsc >> 16) << 7;

            const float* rp = rbf_s + (lbase + i) * NRBF;
            const float2 f01 = *reinterpret_cast<const float2*>(rp + 0);
            const float2 f23 = *reinterpret_cast<const float2*>(rp + 2);
            const float2 f45 = *reinterpret_cast<const float2*>(rp + 4);

            float4 acc = *reinterpret_cast<const float4*>(T1s + za + d);
            const float4 t2 = *reinterpret_cast<const float4*>(T2s + zb + d);
            acc.x += t2.x; acc.y += t2.y; acc.z += t2.z; acc.w += t2.w;

            acc.x += f01.x * wc0.x; acc.y += f01.x * wc0.y; acc.z += f01.x * wc0.z; acc.w += f01.x * wc0.w;
            acc.x += f01.y * wc1.x; acc.y += f01.y * wc1.y; acc.z += f01.y * wc1.z; acc.w += f01.y * wc1.w;
            acc.x += f23.x * wc2.x; acc.y += f23.x * wc2.y; acc.z += f23.x * wc2.z; acc.w += f23.x * wc2.w;
            acc.x += f23.y * wc3.x; acc.y += f23.y * wc3.y; acc.z += f23.y * wc3.z; acc.w += f23.y * wc3.w;
            acc.x += f45.x * wc4.x; acc.y += f45.x * wc4.y; acc.z += f45.x * wc4.z; acc.w += f45.x * wc4.w;
            acc.x += f45.y * wc5.x; acc.y += f45.y * wc5.y; acc.z += f45.y * wc5.z; acc.w += f45.y * wc5.w;

            float4 rr;
            rr.x = acc.x * __builtin_amdgcn_rcpf(1.0f + __expf(-acc.x));
            rr.y = acc.y * __builtin_amdgcn_rcpf(1.0f + __expf(-acc.y));
            rr.z = acc.z * __builtin_amdgcn_rcpf(1.0f + __expf(-acc.z));
            rr.w = acc.w * __builtin_amdgcn_rcpf(1.0f + __expf(-acc.w));

            *reinterpret_cast<float4*>(out + (long)e * EMBED + d) = rr;
        }
    };

    // ---- consume half 0 ----
    compute_half(base);
    __syncthreads();

    // ---- stage half 1 inputs ----
    {
        const int src0 = ((base + HALF) * NRBF) >> 2;
        float4* dst = reinterpret_cast<float4*>(rbf_s);
        #pragma unroll 2
        for (int i = tid; i < RBF_F / 4; i += EBLOCK) {
            const int s = src0 + i;
            dst[i] = (s < nf4) ? erbf4[s] : make_float4(0.f, 0.f, 0.f, 0.f);
        }
        #pragma unroll 2
        for (int i = tid; i < HALF; i += EBLOCK) {
            const int e = base + HALF + i;
            if (e < E) {
                const int2 nn = *reinterpret_cast<const int2*>(nbr + 2 * e);
                desc_s[i] = z[nn.x] | (z[nn.y] << 16);
            }
        }
    }
    __syncthreads();

    // ---- consume half 1 ----
    compute_half(base + HALF);
}

extern "C" void kernel_launch(void* const* d_in, const int* in_sizes, int n_in,
                              void* d_out, int out_size, void* d_ws, size_t ws_size,
                              hipStream_t stream)
{
    // Input order: e_rbf, z, nbr_list, W_edge, emb_table, W_dense, b_dense
    const float* e_rbf  = (const float*)d_in[0];
    const int*   z      = (const int*)  d_in[1];
    const int*   nbr    = (const int*)  d_in[2];
    const float* W_edge = (const float*)d_in[3];
    const float* emb    = (const float*)d_in[4];
    const float* Wd     = (const float*)d_in[5];
    const float* b      = (const float*)d_in[6];
    float* out = (float*)d_out;

    const int E = in_sizes[2] / 2;

    float* T1 = (float*)d_ws;
    float* T2 = T1 + VOCAB * EMBED;
    float* Wc = T2 + VOCAB * EMBED;

    precompute_kernel<<<VOCAB + NRBF, EMBED, 0, stream>>>(W_edge, emb, Wd, b, T1, T2, Wc);

    const int grid = (E + BCHUNK - 1) / BCHUNK;   // 254 for E=600000
    edge_kernel<<<grid, EBLOCK, SMEM_BYTES, stream>>>(e_rbf, z, nbr, T1, out, E);
}

// Round 8
// 78.959 us; speedup vs baseline: 9.9449x; 1.0517x over previous
//
#include <hip/hip_runtime.h>
#include <hip/hip_fp16.h>

#define EMBED 128
#define NRBF 6
#define VOCAB 100
#define EBLOCK 1024
#define GROUPS 32                  // 32-lane groups per block
#define CPG 37                     // edges per group per half
#define HALF (GROUPS * CPG)        // 1184 edges per half
#define BCHUNK (2 * HALF)          // 2368 edges per block
#define TABLE_F (VOCAB * EMBED * 2 + NRBF * EMBED)   // 26368 floats = 105,472 B
#define SMEM_BYTES (TABLE_F * 4 + HALF * 16)         // + meta uint4[1184] = 124,416 B

// ---------------------------------------------------------------------------
// Precompute, parallel over 206 blocks:
//   blocks 0..99   : T1[v][d] = sum_j emb[v][j]*Wd[j][d] + b[d]
//   blocks 100..199: T2[v][d] = sum_j emb[v][j]*Wd[128+j][d]
//   blocks 200..205: Wc[k][d] = sum_j W_edge[k][j]*Wd[256+j][d]
// ---------------------------------------------------------------------------
__global__ __launch_bounds__(EMBED) void precompute_kernel(
    const float* __restrict__ W_edge,
    const float* __restrict__ emb,
    const float* __restrict__ Wd,
    const float* __restrict__ b,
    float* __restrict__ T1,
    float* __restrict__ T2,
    float* __restrict__ Wc)
{
    const int d = threadIdx.x;
    const int v = blockIdx.x;
    if (v < 2 * VOCAB) {
        const int row = (v < VOCAB) ? v : v - VOCAB;
        const int woff = (v < VOCAB) ? 0 : EMBED;
        __shared__ float hrow[EMBED];
        hrow[d] = emb[row * EMBED + d];
        __syncthreads();
        float acc = (v < VOCAB) ? b[d] : 0.0f;
        #pragma unroll 8
        for (int j = 0; j < EMBED; ++j)
            acc += hrow[j] * Wd[(woff + j) * EMBED + d];
        if (v < VOCAB) T1[row * EMBED + d] = acc;
        else           T2[row * EMBED + d] = acc;
    } else {
        const int k = v - 2 * VOCAB;
        float acc = 0.0f;
        #pragma unroll 8
        for (int j = 0; j < EMBED; ++j)
            acc += W_edge[k * EMBED + j] * Wd[(2 * EMBED + j) * EMBED + d];
        Wc[k * EMBED + d] = acc;
    }
}

// ---------------------------------------------------------------------------
// Edge kernel. Per block: 2368 contiguous edges in two halves.
// Per-edge LDS metadata packed to ONE uint4: {rbf as 6xfp16, za|zb<<16}.
// Consume loop: 3 LDS instructions per edge (meta b128 broadcast, T1 b128,
// T2 b128) + one contiguous-1KB-per-wave float4 store. Half-1 global inputs
// prefetched into registers before consume-0 (issue-early / write-late).
// ---------------------------------------------------------------------------
__global__ __launch_bounds__(EBLOCK) void edge_kernel(
    const float* __restrict__ e_rbf,   // [E,6]
    const int*   __restrict__ z,       // [N]
    const int*   __restrict__ nbr,     // [E,2]
    const float* __restrict__ tables,  // T1|T2|Wc in ws
    float* __restrict__ out,           // [E,128]
    int E)
{
    extern __shared__ float smem[];
    float* T1s = smem;                          // [100*128]
    float* T2s = smem + VOCAB * EMBED;          // [100*128]
    float* Wcs = smem + 2 * VOCAB * EMBED;      // [6*128]
    uint4* meta = (uint4*)(smem + TABLE_F);     // [1184]

    const int tid  = threadIdx.x;
    const int base = blockIdx.x * BCHUNK;
    const int lane = tid & 31;
    const int d    = lane * 4;
    const int g    = tid >> 5;

    // ---- stage tables ----
    {
        const float4* src = reinterpret_cast<const float4*>(tables);
        float4* dst = reinterpret_cast<float4*>(smem);
        #pragma unroll 2
        for (int i = tid; i < TABLE_F / 4; i += EBLOCK)
            dst[i] = src[i];
    }

    // ---- stage half-0 meta directly ----
    {
        // slot A: idx = tid ; slot B: idx = tid + 1024 (only tid < 160)
        for (int s = 0; s < 2; ++s) {
            const int idx = tid + s * EBLOCK;
            if (idx >= HALF) break;
            const int e = base + idx;
            uint4 m = make_uint4(0u, 0u, 0u, 0u);
            if (e < E) {
                const int2 nn = *reinterpret_cast<const int2*>(nbr + 2 * e);
                const float* rp = e_rbf + (long)e * NRBF;
                const float2 a = *reinterpret_cast<const float2*>(rp + 0);
                const float2 bb = *reinterpret_cast<const float2*>(rp + 2);
                const float2 c = *reinterpret_cast<const float2*>(rp + 4);
                __half2 ha = __float22half2_rn(a);
                __half2 hb = __float22half2_rn(bb);
                __half2 hc = __float22half2_rn(c);
                m.x = *reinterpret_cast<unsigned*>(&ha);
                m.y = *reinterpret_cast<unsigned*>(&hb);
                m.z = *reinterpret_cast<unsigned*>(&hc);
                m.w = (unsigned)z[nn.x] | ((unsigned)z[nn.y] << 16);
            }
            meta[idx] = m;
        }
    }

    // ---- prefetch half-1 raw inputs into registers (issue-early) ----
    int2  nnA = make_int2(0, 0);
    float2 rA0 = make_float2(0.f, 0.f), rA1 = rA0, rA2 = rA0;
    int2  nnB = make_int2(0, 0);
    float2 rB0 = make_float2(0.f, 0.f), rB1 = rB0, rB2 = rB0;
    const int eA = base + HALF + tid;
    const bool vA = (eA < E);
    const int eB = base + HALF + EBLOCK + tid;
    const bool vB = (tid < HALF - EBLOCK) && (eB < E);
    if (vA) {
        nnA = *reinterpret_cast<const int2*>(nbr + 2 * eA);
        const float* rp = e_rbf + (long)eA * NRBF;
        rA0 = *reinterpret_cast<const float2*>(rp + 0);
        rA1 = *reinterpret_cast<const float2*>(rp + 2);
        rA2 = *reinterpret_cast<const float2*>(rp + 4);
    }
    if (vB) {
        nnB = *reinterpret_cast<const int2*>(nbr + 2 * eB);
        const float* rp = e_rbf + (long)eB * NRBF;
        rB0 = *reinterpret_cast<const float2*>(rp + 0);
        rB1 = *reinterpret_cast<const float2*>(rp + 2);
        rB2 = *reinterpret_cast<const float2*>(rp + 4);
    }
    __syncthreads();

    // Wc into registers (stable for whole kernel)
    const float4 wc0 = *reinterpret_cast<const float4*>(Wcs + 0 * EMBED + d);
    const float4 wc1 = *reinterpret_cast<const float4*>(Wcs + 1 * EMBED + d);
    const float4 wc2 = *reinterpret_cast<const float4*>(Wcs + 2 * EMBED + d);
    const float4 wc3 = *reinterpret_cast<const float4*>(Wcs + 3 * EMBED + d);
    const float4 wc4 = *reinterpret_cast<const float4*>(Wcs + 4 * EMBED + d);
    const float4 wc5 = *reinterpret_cast<const float4*>(Wcs + 5 * EMBED + d);

    // pair-mapped consume: wave's two groups handle consecutive edges ->
    // each wave64 store is one contiguous 1 KB burst.
    auto consume_half = [&](int ebase) {
        const int lb = (g >> 1) * (2 * CPG) + (g & 1);
        #pragma unroll 4
        for (int i = 0; i < CPG; ++i) {
            const int le = lb + 2 * i;
            const int e = ebase + le;
            if (e >= E) break;

            const uint4 m = meta[le];               // 1x ds_read_b128 (broadcast)
            const float2 f01 = __half22float2(*reinterpret_cast<const __half2*>(&m.x));
            const float2 f23 = __half22float2(*reinterpret_cast<const __half2*>(&m.y));
            const float2 f45 = __half22float2(*reinterpret_cast<const __half2*>(&m.z));
            const int za = (int)(m.w & 0xffffu) << 7;
            const int zb = (int)(m.w >> 16) << 7;

            float4 acc = *reinterpret_cast<const float4*>(T1s + za + d);
            const float4 t2 = *reinterpret_cast<const float4*>(T2s + zb + d);
            acc.x += t2.x; acc.y += t2.y; acc.z += t2.z; acc.w += t2.w;

            acc.x += f01.x * wc0.x; acc.y += f01.x * wc0.y; acc.z += f01.x * wc0.z; acc.w += f01.x * wc0.w;
            acc.x += f01.y * wc1.x; acc.y += f01.y * wc1.y; acc.z += f01.y * wc1.z; acc.w += f01.y * wc1.w;
            acc.x += f23.x * wc2.x; acc.y += f23.x * wc2.y; acc.z += f23.x * wc2.z; acc.w += f23.x * wc2.w;
            acc.x += f23.y * wc3.x; acc.y += f23.y * wc3.y; acc.z += f23.y * wc3.z; acc.w += f23.y * wc3.w;
            acc.x += f45.x * wc4.x; acc.y += f45.x * wc4.y; acc.z += f45.x * wc4.z; acc.w += f45.x * wc4.w;
            acc.x += f45.y * wc5.x; acc.y += f45.y * wc5.y; acc.z += f45.y * wc5.z; acc.w += f45.y * wc5.w;

            float4 rr;
            rr.x = acc.x * __builtin_amdgcn_rcpf(1.0f + __expf(-acc.x));
            rr.y = acc.y * __builtin_amdgcn_rcpf(1.0f + __expf(-acc.y));
            rr.z = acc.z * __builtin_amdgcn_rcpf(1.0f + __expf(-acc.z));
            rr.w = acc.w * __builtin_amdgcn_rcpf(1.0f + __expf(-acc.w));

            *reinterpret_cast<float4*>(out + (long)e * EMBED + d) = rr;
        }
    };

    // ---- consume half 0 ----
    consume_half(base);
    __syncthreads();

    // ---- finish half-1 meta (z-gather + pack + ds_write) ----
    {
        if (tid < HALF) {   // slot A
            uint4 m = make_uint4(0u, 0u, 0u, 0u);
            if (vA) {
                __half2 ha = __float22half2_rn(rA0);
                __half2 hb = __float22half2_rn(rA1);
                __half2 hc = __float22half2_rn(rA2);
                m.x = *reinterpret_cast<unsigned*>(&ha);
                m.y = *reinterpret_cast<unsigned*>(&hb);
                m.z = *reinterpret_cast<unsigned*>(&hc);
                m.w = (unsigned)z[nnA.x] | ((unsigned)z[nnA.y] << 16);
            }
            meta[tid] = m;
        }
        if (tid < HALF - EBLOCK) {   // slot B (tid < 160)
            uint4 m = make_uint4(0u, 0u, 0u, 0u);
            if (vB) {
                __half2 ha = __float22half2_rn(rB0);
                __half2 hb = __float22half2_rn(rB1);
                __half2 hc = __float22half2_rn(rB2);
                m.x = *reinterpret_cast<unsigned*>(&ha);
                m.y = *reinterpret_cast<unsigned*>(&hb);
                m.z = *reinterpret_cast<unsigned*>(&hc);
                m.w = (unsigned)z[nnB.x] | ((unsigned)z[nnB.y] << 16);
            }
            meta[EBLOCK + tid] = m;
        }
    }
    __syncthreads();

    // ---- consume half 1 ----
    consume_half(base + HALF);
}

extern "C" void kernel_launch(void* const* d_in, const int* in_sizes, int n_in,
                              void* d_out, int out_size, void* d_ws, size_t ws_size,
                              hipStream_t stream)
{
    // Input order: e_rbf, z, nbr_list, W_edge, emb_table, W_dense, b_dense
    const float* e_rbf  = (const float*)d_in[0];
    const int*   z      = (const int*)  d_in[1];
    const int*   nbr    = (const int*)  d_in[2];
    const float* W_edge = (const float*)d_in[3];
    const float* emb    = (const float*)d_in[4];
    const float* Wd     = (const float*)d_in[5];
    const float* b      = (const float*)d_in[6];
    float* out = (float*)d_out;

    const int E = in_sizes[2] / 2;

    float* T1 = (float*)d_ws;
    float* T2 = T1 + VOCAB * EMBED;
    float* Wc = T2 + VOCAB * EMBED;

    precompute_kernel<<<2 * VOCAB + NRBF, EMBED, 0, stream>>>(W_edge, emb, Wd, b, T1, T2, Wc);

    const int grid = (E + BCHUNK - 1) / BCHUNK;   // 254 for E=600000
    edge_kernel<<<grid, EBLOCK, SMEM_BYTES, stream>>>(e_rbf, z, nbr, T1, out, E);
}